// Round 8
// baseline (865.945 us; speedup 1.0000x reference)
//
#include <hip/hip_runtime.h>
#include <math.h>

#define BB 64
#define TT 1024
#define DD 32
#define GG 128   // 4*D
#define VOCABN 10000
#define QLEN 100

typedef float f32x2 __attribute__((ext_vector_type(2)));
typedef short short8 __attribute__((ext_vector_type(8)));   // 8 bf16 in 4 VGPRs
typedef float floatx4 __attribute__((ext_vector_type(4)));

__device__ __forceinline__ float fsig(float x) {
    return __builtin_amdgcn_rcpf(1.0f + __expf(-x));
}
__device__ __forceinline__ short f2bf_rne(float x) {
    unsigned u = __float_as_uint(x);
    u += 0x7FFF + ((u >> 16) & 1);
    return (short)(u >> 16);
}
__device__ __forceinline__ float bf2f(short s) {
    return __uint_as_float(((unsigned)(unsigned short)s) << 16);
}

// ---------------------------------------------------------------------------
// Kernel 1: xg[b,t,j] = b_lstm[j] + sum_d emb[id[b,t],d] * k_lstm[d,j]
// ---------------------------------------------------------------------------
__global__ __launch_bounds__(128) void k_xg(const int* __restrict__ ids,
                                            const float* __restrict__ emb,
                                            const float* __restrict__ klstm,
                                            const float* __restrict__ bias,
                                            float* __restrict__ xg) {
    const int j = threadIdx.x;  // 0..127
    float kc[DD];
#pragma unroll
    for (int d = 0; d < DD; ++d) kc[d] = klstm[d * GG + j];
    const float bj = bias[j];
    __shared__ float e4[4][DD];
    const int PPB = (BB * TT) / gridDim.x;  // 128 tokens per block
    const int p0 = blockIdx.x * PPB;
    for (int p = p0; p < p0 + PPB; p += 4) {
        {
            int tok = p + (j >> 5);
            int id = ids[tok];
            if ((unsigned)id >= VOCABN) id = 0;
            e4[j >> 5][j & 31] = emb[id * DD + (j & 31)];
        }
        __syncthreads();
#pragma unroll
        for (int i = 0; i < 4; ++i) {
            float z = bj;
#pragma unroll
            for (int d = 0; d < DD; ++d) z += e4[i][d] * kc[d];
            xg[(size_t)(p + i) * GG + j] = z;
        }
        __syncthreads();
    }
}

// ---------------------------------------------------------------------------
// Kernel 2: LSTM scan via MFMA. One wave per batch.
// z(1x128) = h(1x32)·RK(32x128) done as 8 16x16x32 bf16 MFMA tiles with a
// 3-term bf16-split (hi*hi + hi*lo + lo*hi) for ~fp32 accuracy.
// Trick: every lane loads the SAME h-chunk for its k-slot -> all A rows
// identical -> all C rows identical -> every lane holds z for col
// 16c+(lane&15) in acc[0]. Each lane then owns all 4 gates for dims
// n=lane&15 and n+16: no cross-lane shfl at all. h round-trips through a
// 32-float LDS buffer (same-wave ds ordering, no barrier).
// xg streamed with 2-step-ahead register prefetch, added post-MFMA.
// ---------------------------------------------------------------------------
#define LSTM_STEP(t_, XBUF, TP)                                               \
    {                                                                         \
        float4 h0 = *(const float4*)&hlds[kb];                                \
        float4 h1 = *(const float4*)&hlds[kb + 4];                            \
        float hv[8] = {h0.x, h0.y, h0.z, h0.w, h1.x, h1.y, h1.z, h1.w};       \
        short8 ah, al;                                                        \
        _Pragma("unroll")                                                     \
        for (int j = 0; j < 8; ++j) {                                         \
            short hi16 = f2bf_rne(hv[j]);                                     \
            ah[j] = hi16;                                                     \
            al[j] = f2bf_rne(hv[j] - bf2f(hi16));                             \
        }                                                                     \
        float z[8];                                                           \
        _Pragma("unroll")                                                     \
        for (int c = 0; c < 8; ++c) {                                         \
            floatx4 acc = {0.f, 0.f, 0.f, 0.f};                               \
            acc = __builtin_amdgcn_mfma_f32_16x16x32_bf16(ah, bh[c], acc, 0, 0, 0); \
            acc = __builtin_amdgcn_mfma_f32_16x16x32_bf16(ah, bl[c], acc, 0, 0, 0); \
            acc = __builtin_amdgcn_mfma_f32_16x16x32_bf16(al, bh[c], acc, 0, 0, 0); \
            z[c] = acc[0] + XBUF[c];                                          \
        }                                                                     \
        {                                                                     \
            int tp = (TP) > TT - 1 ? TT - 1 : (TP);                           \
            _Pragma("unroll")                                                 \
            for (int c = 0; c < 8; ++c) XBUF[c] = xgb[tp * GG + 16 * c + n];  \
        }                                                                     \
        float iA = fsig(z[0]), iB = fsig(z[1]);                               \
        float fA = fsig(z[2]), fB = fsig(z[3]);                               \
        float gA = 2.f * fsig(2.f * z[4]) - 1.f;                              \
        float gB = 2.f * fsig(2.f * z[5]) - 1.f;                              \
        float oA = fsig(z[6]), oB = fsig(z[7]);                               \
        c1 = fmaf(fA, c1, iA * gA);                                           \
        c2 = fmaf(fB, c2, iB * gB);                                           \
        float h1v = oA * (2.f * fsig(2.f * c1) - 1.f);                        \
        float h2v = oB * (2.f * fsig(2.f * c2) - 1.f);                        \
        if (l < 16) {                                                         \
            hlds[n] = h1v; hlds[n + 16] = h2v;                                \
            hb[(t_) * DD + n] = h1v; hb[(t_) * DD + n + 16] = h2v;            \
        }                                                                     \
    }

__global__
__attribute__((amdgpu_flat_work_group_size(64, 64)))
__attribute__((amdgpu_waves_per_eu(1, 1)))
void k_lstm_scan(const float* __restrict__ xg,
                 const float* __restrict__ rk,
                 float* __restrict__ hout) {
    const int b = blockIdx.x;
    const int l = threadIdx.x;   // 0..63
    const int n = l & 15;        // col within tile == dim (and dim+16)
    const int kb = (l >> 4) * 8; // k-chunk base for A/B fragments

    // B fragments: tile c covers gate cols [16c, 16c+16). B[k][col]:
    // lane holds k = kb+j, col = 16c+n. hi/lo bf16 split.
    short8 bh[8], bl[8];
#pragma unroll
    for (int c = 0; c < 8; ++c) {
#pragma unroll
        for (int j = 0; j < 8; ++j) {
            float v = rk[(kb + j) * GG + 16 * c + n];
            short hi16 = f2bf_rne(v);
            bh[c][j] = hi16;
            bl[c][j] = f2bf_rne(v - bf2f(hi16));
        }
    }

    __shared__ __align__(16) float hlds[DD];
    if (l < 16) { hlds[n] = 0.0f; hlds[n + 16] = 0.0f; }

    const float* xgb = xg + (size_t)b * TT * GG;
    float* hb = hout + (size_t)b * TT * DD;

    float xA[8], xB[8];
#pragma unroll
    for (int c = 0; c < 8; ++c) {
        xA[c] = xgb[0 * GG + 16 * c + n];
        xB[c] = xgb[1 * GG + 16 * c + n];
    }

    float c1 = 0.0f, c2 = 0.0f;
    for (int t = 0; t < TT; t += 2) {
        LSTM_STEP(t, xA, t + 2)
        LSTM_STEP(t + 1, xB, t + 3)
    }
}

// ---------------------------------------------------------------------------
// Kernel 3: attention — R6 version (f32x2 / v_pk_fma_f32, split-K flash,
// no max-subtraction: |score|<=32 so exp can't overflow). UNCHANGED.
// ---------------------------------------------------------------------------
__global__ __launch_bounds__(256, 4) void k_attn(const float* __restrict__ h,
                                                 float* __restrict__ ctx) {
    __shared__ float smem[4 * 64 * DD];  // 32 KB: 4 wave-private key tiles
    const int tid = threadIdx.x;
    const int w = tid >> 6;     // split / wave id
    const int lane = tid & 63;  // q row within tile
    const int b = blockIdx.x >> 4;
    const int qt = blockIdx.x & 15;
    const float* hb = h + (size_t)b * TT * DD;
    const int q = qt * 64 + lane;

    f32x2 qq[16], aa[16];
    {
        const float4* qsrc = (const float4*)(hb + (size_t)q * DD);
#pragma unroll
        for (int n = 0; n < 8; ++n) {
            float4 v = qsrc[n];
            qq[2 * n]     = (f32x2){v.x, v.y};
            qq[2 * n + 1] = (f32x2){v.z, v.w};
        }
    }
#pragma unroll
    for (int n = 0; n < 16; ++n) aa[n] = (f32x2){0.0f, 0.0f};
    float l = 0.0f;

    float* myk = smem + w * (64 * DD);
#pragma unroll 1
    for (int tile = 0; tile < 4; ++tile) {
        const float4* ksrc = (const float4*)(hb + (size_t)(w * 256 + tile * 64) * DD);
        float4* kd = (float4*)myk;
#pragma unroll
        for (int n = 0; n < 8; ++n) kd[lane + n * 64] = ksrc[lane + n * 64];
        // wave-private region: same-wave ds write->read ordering, no barrier
        for (int s = 0; s < 64; ++s) {
            const float4* kr = (const float4*)(myk + s * DD);
            f32x2 kk[16];
#pragma unroll
            for (int n = 0; n < 8; ++n) {
                float4 v = kr[n];
                kk[2 * n]     = (f32x2){v.x, v.y};
                kk[2 * n + 1] = (f32x2){v.z, v.w};
            }
            f32x2 d0 = {0.f, 0.f}, d1 = {0.f, 0.f}, d2 = {0.f, 0.f}, d3 = {0.f, 0.f};
#pragma unroll
            for (int n = 0; n < 16; n += 4) {
                d0 = __builtin_elementwise_fma(kk[n],     qq[n],     d0);
                d1 = __builtin_elementwise_fma(kk[n + 1], qq[n + 1], d1);
                d2 = __builtin_elementwise_fma(kk[n + 2], qq[n + 2], d2);
                d3 = __builtin_elementwise_fma(kk[n + 3], qq[n + 3], d3);
            }
            f32x2 ds = (d0 + d1) + (d2 + d3);
            float sc = ds.x + ds.y;
            float e = __expf(sc);
            l += e;
            f32x2 e2 = {e, e};
#pragma unroll
            for (int n = 0; n < 16; ++n)
                aa[n] = __builtin_elementwise_fma(e2, kk[n], aa[n]);
        }
    }

    const float* av = (const float*)aa;
    float* macc = smem;
    for (int ww = 0; ww < 4; ++ww) {
        __syncthreads();
        if (w == ww) {
            if (ww == 0) {
#pragma unroll
                for (int n = 0; n < DD; ++n) macc[lane * 33 + n] = av[n];
                macc[lane * 33 + 32] = l;
            } else {
#pragma unroll
                for (int n = 0; n < DD; ++n) macc[lane * 33 + n] += av[n];
                macc[lane * 33 + 32] += l;
            }
        }
    }
    __syncthreads();
    {
        const int r = tid >> 2;          // 0..63
        const int c0 = (tid & 3) * 8;    // 0,8,16,24
        float linv = __builtin_amdgcn_rcpf(macc[r * 33 + 32]);
        float o[8];
#pragma unroll
        for (int jj = 0; jj < 8; ++jj) o[jj] = macc[r * 33 + c0 + jj] * linv;
        float* crow = ctx + (size_t)b * TT * DD + (size_t)qt * 64 * DD;
        ((float4*)(crow + tid * 8))[0] = make_float4(o[0], o[1], o[2], o[3]);
        ((float4*)(crow + tid * 8))[1] = make_float4(o[4], o[5], o[6], o[7]);
    }
}

// ---------------------------------------------------------------------------
// Kernel 4: y[b,d,e] = sum_t ctx[b,t,d]*h[b,t,e];  yr = relu(y@W1+b1);
// out[b,d] = sigmoid(yr@W2+b2).  One block per batch, 256 threads.
// ---------------------------------------------------------------------------
__global__ __launch_bounds__(256) void k_ymlp(const float* __restrict__ ctx,
                                              const float* __restrict__ h,
                                              const float* __restrict__ W1,
                                              const float* __restrict__ b1,
                                              const float* __restrict__ W2,
                                              const float* __restrict__ b2,
                                              float* __restrict__ out) {
    const int b = blockIdx.x;
    const int tid = threadIdx.x;
    __shared__ __align__(16) float cs[128 * DD];
    __shared__ __align__(16) float hs[128 * DD];
    const float* cb = ctx + (size_t)b * TT * DD;
    const float* hb = h + (size_t)b * TT * DD;
    const int e = tid & 31;
    const int d0 = tid >> 5;
    float acc[4] = {0.f, 0.f, 0.f, 0.f};
    for (int kt = 0; kt < 8; ++kt) {
        const float4* s1 = (const float4*)(cb + (size_t)kt * 128 * DD);
        const float4* s2 = (const float4*)(hb + (size_t)kt * 128 * DD);
        float4* t1 = (float4*)cs;
        float4* t2 = (float4*)hs;
#pragma unroll
        for (int n = 0; n < 4; ++n) {
            t1[tid + n * 256] = s1[tid + n * 256];
            t2[tid + n * 256] = s2[tid + n * 256];
        }
        __syncthreads();
        for (int s = 0; s < 128; ++s) {
            float hv = hs[s * DD + e];
#pragma unroll
            for (int r = 0; r < 4; ++r) acc[r] += cs[s * DD + d0 + 8 * r] * hv;
        }
        __syncthreads();
    }
    __shared__ float ys[DD][DD];
#pragma unroll
    for (int r = 0; r < 4; ++r) ys[d0 + 8 * r][e] = acc[r];
    __syncthreads();
    __shared__ float yr[DD][33];
#pragma unroll
    for (int r = 0; r < 4; ++r) {
        float v = b1[e];
#pragma unroll
        for (int ee = 0; ee < DD; ++ee) v += ys[d0 + 8 * r][ee] * W1[ee * DD + e];
        yr[d0 + 8 * r][e] = fmaxf(v, 0.0f);
    }
    __syncthreads();
    if (tid < DD) {
        float v = b2[0];
#pragma unroll
        for (int ee = 0; ee < DD; ++ee) v += yr[tid][ee] * W2[ee];
        out[b * DD + tid] = 1.0f / (1.0f + expf(-v));
    }
}

// ---------------------------------------------------------------------------
// Kernel 5: zero-index queue. int4 loads + wave shfl-scan.
// ---------------------------------------------------------------------------
__global__ __launch_bounds__(256) void k_queue(const int* __restrict__ ids,
                                               int* __restrict__ list,
                                               float* __restrict__ outq) {
    const int tid = threadIdx.x;
    const int lane = tid & 63;
    const int wv = tid >> 6;
    const int N = BB * TT;       // 65536
    const int CHUNK = N / 256;   // 256 ints = 64 int4
    const int4* v4 = (const int4*)ids;
    const int b4 = tid * (CHUNK / 4);

    int cnt = 0;
#pragma unroll 4
    for (int i = 0; i < CHUNK / 4; ++i) {
        int4 v = v4[b4 + i];
        cnt += (v.x == 0 || (unsigned)v.x >= VOCABN);
        cnt += (v.y == 0 || (unsigned)v.y >= VOCABN);
        cnt += (v.z == 0 || (unsigned)v.z >= VOCABN);
        cnt += (v.w == 0 || (unsigned)v.w >= VOCABN);
    }
    int scan = cnt;
#pragma unroll
    for (int off = 1; off < 64; off <<= 1) {
        int nn = __shfl_up(scan, off);
        if (lane >= off) scan += nn;
    }
    __shared__ int wtot[4], wexcl[4];
    __shared__ int total;
    if (lane == 63) wtot[wv] = scan;
    __syncthreads();
    if (tid == 0) {
        int run = 0;
#pragma unroll
        for (int i = 0; i < 4; ++i) { wexcl[i] = run; run += wtot[i]; }
        total = run;
    }
    __syncthreads();
    int off = wexcl[wv] + scan - cnt;

    const int base = tid * CHUNK;
#pragma unroll 4
    for (int i = 0; i < CHUNK / 4; ++i) {
        int4 v = v4[b4 + i];
        if (v.x == 0 || (unsigned)v.x >= VOCABN) list[off++] = base + 4 * i;
        if (v.y == 0 || (unsigned)v.y >= VOCABN) list[off++] = base + 4 * i + 1;
        if (v.z == 0 || (unsigned)v.z >= VOCABN) list[off++] = base + 4 * i + 2;
        if (v.w == 0 || (unsigned)v.w >= VOCABN) list[off++] = base + 4 * i + 3;
    }
    __syncthreads();
    if (tid < QLEN) {
        const int K = total;
        const int Kc = K < QLEN ? K : QLEN;
        float ii = -1.0f, jj = -1.0f;
        if (tid >= QLEN - Kc) {
            int pos = list[K - QLEN + tid];
            ii = (float)(pos >> 10);
            jj = (float)(pos & (TT - 1));
        }
        outq[2 * tid] = ii;
        outq[2 * tid + 1] = jj;
    }
}

// ---------------------------------------------------------------------------
extern "C" void kernel_launch(void* const* d_in, const int* in_sizes, int n_in,
                              void* d_out, int out_size, void* d_ws, size_t ws_size,
                              hipStream_t stream) {
    const int* ids   = (const int*)d_in[0];
    const float* emb = (const float*)d_in[1];
    const float* kl  = (const float*)d_in[2];
    const float* rk  = (const float*)d_in[3];
    const float* bl  = (const float*)d_in[4];
    const float* W1  = (const float*)d_in[5];
    const float* b1  = (const float*)d_in[6];
    const float* W2  = (const float*)d_in[7];
    const float* b2  = (const float*)d_in[8];
    float* out = (float*)d_out;

    char* ws = (char*)d_ws;
    const size_t XG_ELEMS = (size_t)BB * TT * GG;   // 8,388,608
    const size_t H_ELEMS  = (size_t)BB * TT * DD;   // 2,097,152
    float* xg   = (float*)ws;
    float* h    = (float*)(ws + XG_ELEMS * 4);
    float* ctx  = (float*)(ws + (XG_ELEMS + H_ELEMS) * 4);
    int* list   = (int*)  (ws + (XG_ELEMS + 2 * H_ELEMS) * 4);

    k_xg<<<512, 128, 0, stream>>>(ids, emb, kl, bl, xg);
    k_lstm_scan<<<BB, 64, 0, stream>>>(xg, rk, h);
    k_attn<<<BB * 16, 256, 0, stream>>>(h, ctx);
    k_ymlp<<<BB, 256, 0, stream>>>(ctx, h, W1, b1, W2, b2, out);
    k_queue<<<1, 256, 0, stream>>>(ids, list, out + BB * DD);
}

// Round 9
// 560.749 us; speedup vs baseline: 1.5443x; 1.5443x over previous
//
#include <hip/hip_runtime.h>
#include <math.h>

#define BB 64
#define TT 1024
#define DD 32
#define GG 128   // 4*D
#define VOCABN 10000
#define QLEN 100

typedef float f32x2 __attribute__((ext_vector_type(2)));

__device__ __forceinline__ float fsig(float x) {
    return __builtin_amdgcn_rcpf(1.0f + __expf(-x));
}
__device__ __forceinline__ float readlane_f(float v, int l) {
    return __int_as_float(__builtin_amdgcn_readlane(__float_as_int(v), l));
}

// ---------------------------------------------------------------------------
// Kernel 1: xg[b,t,j] = b_lstm[j] + sum_d emb[id[b,t],d] * k_lstm[d,j]
// ---------------------------------------------------------------------------
__global__ __launch_bounds__(128) void k_xg(const int* __restrict__ ids,
                                            const float* __restrict__ emb,
                                            const float* __restrict__ klstm,
                                            const float* __restrict__ bias,
                                            float* __restrict__ xg) {
    const int j = threadIdx.x;  // 0..127
    float kc[DD];
#pragma unroll
    for (int d = 0; d < DD; ++d) kc[d] = klstm[d * GG + j];
    const float bj = bias[j];
    __shared__ float e4[4][DD];
    const int PPB = (BB * TT) / gridDim.x;  // 128 tokens per block
    const int p0 = blockIdx.x * PPB;
    for (int p = p0; p < p0 + PPB; p += 4) {
        {
            int tok = p + (j >> 5);
            int id = ids[tok];
            if ((unsigned)id >= VOCABN) id = 0;
            e4[j >> 5][j & 31] = emb[id * DD + (j & 31)];
        }
        __syncthreads();
#pragma unroll
        for (int i = 0; i < 4; ++i) {
            float z = bj;
#pragma unroll
            for (int d = 0; d < DD; ++d) z += e4[i][d] * kc[d];
            xg[(size_t)(p + i) * GG + j] = z;
        }
        __syncthreads();
    }
}

// ---------------------------------------------------------------------------
// Kernel 2: LSTM scan — EXACT R3 body (measured 311 µs, VGPR 132) with the
// zero-index queue fused in as block 64: the LSTM occupies only 64 CUs for
// ~311 µs, so the single-block queue rides in its shadow for free.
// R7 lesson (recorded): MFMA on a serial recurrence = latency chain, 2x
// slower. R5 lesson: multi-batch-per-wave starves CUs. This is the floor
// for the scan shape (~730 cyc/step).
// ---------------------------------------------------------------------------
#define UU 8
__global__
__attribute__((amdgpu_flat_work_group_size(64, 64)))
__attribute__((amdgpu_waves_per_eu(1, 1)))
void k_lstm_scan(const float* __restrict__ xg,
                 const float* __restrict__ rk,
                 float* __restrict__ hout,
                 const int* __restrict__ ids,
                 int* __restrict__ list,
                 float* __restrict__ outq) {
    const int b = blockIdx.x;
    const int l = threadIdx.x;       // 0..63
    if (b >= BB) {
        // ---- fused zero-index queue (single wave) ----
        const int4* v4 = (const int4*)ids;
        const int C4 = (BB * TT) / 4 / 64;   // 256 int4 per lane
        const int b4 = l * C4;
        int cnt = 0;
#pragma unroll 4
        for (int i = 0; i < C4; ++i) {
            int4 v = v4[b4 + i];
            cnt += (v.x == 0 || (unsigned)v.x >= VOCABN);
            cnt += (v.y == 0 || (unsigned)v.y >= VOCABN);
            cnt += (v.z == 0 || (unsigned)v.z >= VOCABN);
            cnt += (v.w == 0 || (unsigned)v.w >= VOCABN);
        }
        int scan = cnt;
#pragma unroll
        for (int o = 1; o < 64; o <<= 1) {
            int nn = __shfl_up(scan, o);
            if (l >= o) scan += nn;
        }
        const int total = __shfl(scan, 63);
        int off = scan - cnt;               // exclusive prefix
        const int base = l * (C4 * 4);
#pragma unroll 4
        for (int i = 0; i < C4; ++i) {
            int4 v = v4[b4 + i];
            if (v.x == 0 || (unsigned)v.x >= VOCABN) list[off++] = base + 4 * i;
            if (v.y == 0 || (unsigned)v.y >= VOCABN) list[off++] = base + 4 * i + 1;
            if (v.z == 0 || (unsigned)v.z >= VOCABN) list[off++] = base + 4 * i + 2;
            if (v.w == 0 || (unsigned)v.w >= VOCABN) list[off++] = base + 4 * i + 3;
        }
        __threadfence();   // drain stores; cross-lane list reads below
        const int Kc = total < QLEN ? total : QLEN;
        for (int t = l; t < QLEN; t += 64) {
            float ii = -1.0f, jj = -1.0f;
            if (t >= QLEN - Kc) {
                int pos = list[total - QLEN + t];
                ii = (float)(pos >> 10);
                jj = (float)(pos & (TT - 1));
            }
            outq[2 * t] = ii;
            outq[2 * t + 1] = jj;
        }
        return;
    }
    // ---- LSTM scan (R3-exact) ----
    const int d = l & 31;
    const bool hi = l >= 32;
    const int ga = (hi ? 32 : 0) + d;   // i (lo) / f (hi)
    const int gb = (hi ? 96 : 64) + d;  // g (lo) / o (hi)
    float rka[DD], rkb[DD];
#pragma unroll
    for (int k = 0; k < DD; ++k) { rka[k] = rk[k * GG + ga]; rkb[k] = rk[k * GG + gb]; }
    const float* xgb = xg + (size_t)b * TT * GG;
    float* hb = hout + (size_t)b * TT * DD;

    float pa[UU], pb[UU];
#pragma unroll
    for (int u = 0; u < UU; ++u) { pa[u] = xgb[u * GG + ga]; pb[u] = xgb[u * GG + gb]; }

    float h = 0.0f, c = 0.0f;
    for (int t0 = 0; t0 < TT; t0 += UU) {
        float na[UU], nb[UU];
        const int tn0 = (t0 + UU < TT) ? (t0 + UU) : t0;
#pragma unroll
        for (int u = 0; u < UU; ++u) {
            na[u] = xgb[(tn0 + u) * GG + ga];
            nb[u] = xgb[(tn0 + u) * GG + gb];
        }
#pragma unroll
        for (int u = 0; u < UU; ++u) {
            float za0 = pa[u], zb0 = pb[u];
            float za1 = 0.f, za2 = 0.f, za3 = 0.f;
            float zb1 = 0.f, zb2 = 0.f, zb3 = 0.f;
#pragma unroll
            for (int k = 0; k < DD; k += 4) {
                float h0 = readlane_f(h, k);
                float h1 = readlane_f(h, k + 1);
                float h2 = readlane_f(h, k + 2);
                float h3 = readlane_f(h, k + 3);
                za0 = fmaf(h0, rka[k], za0);     zb0 = fmaf(h0, rkb[k], zb0);
                za1 = fmaf(h1, rka[k + 1], za1); zb1 = fmaf(h1, rkb[k + 1], zb1);
                za2 = fmaf(h2, rka[k + 2], za2); zb2 = fmaf(h2, rkb[k + 2], zb2);
                za3 = fmaf(h3, rka[k + 3], za3); zb3 = fmaf(h3, rkb[k + 3], zb3);
            }
            float za = (za0 + za1) + (za2 + za3);
            float zb = (zb0 + zb1) + (zb2 + zb3);
            float a = fsig(za);                       // sig(i) lo / sig(f) hi
            float zbm = hi ? zb : 2.0f * zb;
            float s2 = fsig(zbm);
            float bv = hi ? s2 : 2.0f * s2 - 1.0f;    // sig(o) hi / tanh(g) lo
            float fg = __shfl_xor(a, 32);             // lo lanes get sig(f)
            float og = __shfl_xor(bv, 32);            // lo lanes get sig(o)
            c = fmaf(fg, c, a * bv);                  // sig(f)*c + sig(i)*tanh(g)
            float tc = 2.0f * fsig(2.0f * c) - 1.0f;  // tanh(c)
            h = og * tc;
            if (!hi) hb[(t0 + u) * DD + d] = h;
        }
#pragma unroll
        for (int u = 0; u < UU; ++u) { pa[u] = na[u]; pb[u] = nb[u]; }
    }
}

// ---------------------------------------------------------------------------
// Kernel 3: attention — R6 f32x2 structure, now 2 q-rows PER LANE (128 q
// rows per block): the 8 broadcast ds_read_b128 per key feed 2x the FMA
// work, halving the LDS-read + loop-overhead share per unit compute.
// Split-K flash, no max-subtraction (|score|<=32, exp can't overflow).
// ---------------------------------------------------------------------------
__global__ __launch_bounds__(256, 2) void k_attn(const float* __restrict__ h,
                                                 float* __restrict__ ctx) {
    __shared__ float smem[4 * 64 * DD];  // 32 KB tiles; merge area reuses it
    const int tid = threadIdx.x;
    const int w = tid >> 6;     // split / wave id
    const int lane = tid & 63;
    const int b = blockIdx.x >> 3;
    const int qt = blockIdx.x & 7;      // 8 q-tiles of 128 rows
    const float* hb = h + (size_t)b * TT * DD;
    const int q0 = qt * 128 + lane;     // rows q0 and q0+64

    f32x2 qq0[16], qq1[16], aa0[16], aa1[16];
    {
        const float4* s0 = (const float4*)(hb + (size_t)q0 * DD);
        const float4* s1 = (const float4*)(hb + (size_t)(q0 + 64) * DD);
#pragma unroll
        for (int n = 0; n < 8; ++n) {
            float4 v0 = s0[n], v1 = s1[n];
            qq0[2 * n]     = (f32x2){v0.x, v0.y};
            qq0[2 * n + 1] = (f32x2){v0.z, v0.w};
            qq1[2 * n]     = (f32x2){v1.x, v1.y};
            qq1[2 * n + 1] = (f32x2){v1.z, v1.w};
        }
    }
#pragma unroll
    for (int n = 0; n < 16; ++n) {
        aa0[n] = (f32x2){0.0f, 0.0f};
        aa1[n] = (f32x2){0.0f, 0.0f};
    }
    float l0 = 0.0f, l1 = 0.0f;

    float* myk = smem + w * (64 * DD);
#pragma unroll 1
    for (int tile = 0; tile < 4; ++tile) {
        const float4* ksrc = (const float4*)(hb + (size_t)(w * 256 + tile * 64) * DD);
        float4* kd = (float4*)myk;
#pragma unroll
        for (int n = 0; n < 8; ++n) kd[lane + n * 64] = ksrc[lane + n * 64];
        // wave-private region: same-wave ds write->read ordering, no barrier
        for (int s = 0; s < 64; ++s) {
            const float4* kr = (const float4*)(myk + s * DD);
            f32x2 kk[16];
#pragma unroll
            for (int n = 0; n < 8; ++n) {
                float4 v = kr[n];
                kk[2 * n]     = (f32x2){v.x, v.y};
                kk[2 * n + 1] = (f32x2){v.z, v.w};
            }
            f32x2 d0 = {0.f, 0.f}, d1 = {0.f, 0.f};
            f32x2 e0v = {0.f, 0.f}, e1v = {0.f, 0.f};
#pragma unroll
            for (int n = 0; n < 16; n += 2) {
                d0  = __builtin_elementwise_fma(kk[n],     qq0[n],     d0);
                d1  = __builtin_elementwise_fma(kk[n + 1], qq0[n + 1], d1);
                e0v = __builtin_elementwise_fma(kk[n],     qq1[n],     e0v);
                e1v = __builtin_elementwise_fma(kk[n + 1], qq1[n + 1], e1v);
            }
            f32x2 ds0 = d0 + d1, ds1 = e0v + e1v;
            float e0 = __expf(ds0.x + ds0.y);
            float e1 = __expf(ds1.x + ds1.y);
            l0 += e0; l1 += e1;
            f32x2 e02 = {e0, e0}, e12 = {e1, e1};
#pragma unroll
            for (int n = 0; n < 16; ++n) {
                aa0[n] = __builtin_elementwise_fma(e02, kk[n], aa0[n]);
                aa1[n] = __builtin_elementwise_fma(e12, kk[n], aa1[n]);
            }
        }
    }

    // merge splits: sequential adds into macc[128][33] (reuses tile LDS)
    const float* av0 = (const float*)aa0;
    const float* av1 = (const float*)aa1;
    float* macc = smem;
    for (int ww = 0; ww < 4; ++ww) {
        __syncthreads();
        if (w == ww) {
            if (ww == 0) {
#pragma unroll
                for (int n = 0; n < DD; ++n) {
                    macc[lane * 33 + n] = av0[n];
                    macc[(lane + 64) * 33 + n] = av1[n];
                }
                macc[lane * 33 + 32] = l0;
                macc[(lane + 64) * 33 + 32] = l1;
            } else {
#pragma unroll
                for (int n = 0; n < DD; ++n) {
                    macc[lane * 33 + n] += av0[n];
                    macc[(lane + 64) * 33 + n] += av1[n];
                }
                macc[lane * 33 + 32] += l0;
                macc[(lane + 64) * 33 + 32] += l1;
            }
        }
    }
    __syncthreads();
    {
        const int r = tid >> 1;           // 0..127
        const int c0 = (tid & 1) * 16;    // 0 / 16
        float linv = __builtin_amdgcn_rcpf(macc[r * 33 + 32]);
        float* crow = ctx + (size_t)b * TT * DD + (size_t)(qt * 128 + r) * DD + c0;
#pragma unroll
        for (int n = 0; n < 4; ++n) {
            float4 v;
            v.x = macc[r * 33 + c0 + 4 * n] * linv;
            v.y = macc[r * 33 + c0 + 4 * n + 1] * linv;
            v.z = macc[r * 33 + c0 + 4 * n + 2] * linv;
            v.w = macc[r * 33 + c0 + 4 * n + 3] * linv;
            ((float4*)crow)[n] = v;
        }
    }
}

// ---------------------------------------------------------------------------
// Kernel 4: y[b,d,e] = sum_t ctx[b,t,d]*h[b,t,e];  yr = relu(y@W1+b1);
// out[b,d] = sigmoid(yr@W2+b2).  One block per batch, 256 threads.
// ---------------------------------------------------------------------------
__global__ __launch_bounds__(256) void k_ymlp(const float* __restrict__ ctx,
                                              const float* __restrict__ h,
                                              const float* __restrict__ W1,
                                              const float* __restrict__ b1,
                                              const float* __restrict__ W2,
                                              const float* __restrict__ b2,
                                              float* __restrict__ out) {
    const int b = blockIdx.x;
    const int tid = threadIdx.x;
    __shared__ __align__(16) float cs[128 * DD];
    __shared__ __align__(16) float hs[128 * DD];
    const float* cb = ctx + (size_t)b * TT * DD;
    const float* hb = h + (size_t)b * TT * DD;
    const int e = tid & 31;
    const int d0 = tid >> 5;
    float acc[4] = {0.f, 0.f, 0.f, 0.f};
    for (int kt = 0; kt < 8; ++kt) {
        const float4* s1 = (const float4*)(cb + (size_t)kt * 128 * DD);
        const float4* s2 = (const float4*)(hb + (size_t)kt * 128 * DD);
        float4* t1 = (float4*)cs;
        float4* t2 = (float4*)hs;
#pragma unroll
        for (int n = 0; n < 4; ++n) {
            t1[tid + n * 256] = s1[tid + n * 256];
            t2[tid + n * 256] = s2[tid + n * 256];
        }
        __syncthreads();
        for (int s = 0; s < 128; ++s) {
            float hv = hs[s * DD + e];
#pragma unroll
            for (int r = 0; r < 4; ++r) acc[r] += cs[s * DD + d0 + 8 * r] * hv;
        }
        __syncthreads();
    }
    __shared__ float ys[DD][DD];
#pragma unroll
    for (int r = 0; r < 4; ++r) ys[d0 + 8 * r][e] = acc[r];
    __syncthreads();
    __shared__ float yr[DD][33];
#pragma unroll
    for (int r = 0; r < 4; ++r) {
        float v = b1[e];
#pragma unroll
        for (int ee = 0; ee < DD; ++ee) v += ys[d0 + 8 * r][ee] * W1[ee * DD + e];
        yr[d0 + 8 * r][e] = fmaxf(v, 0.0f);
    }
    __syncthreads();
    if (tid < DD) {
        float v = b2[0];
#pragma unroll
        for (int ee = 0; ee < DD; ++ee) v += yr[tid][ee] * W2[ee];
        out[b * DD + tid] = 1.0f / (1.0f + expf(-v));
    }
}

// ---------------------------------------------------------------------------
extern "C" void kernel_launch(void* const* d_in, const int* in_sizes, int n_in,
                              void* d_out, int out_size, void* d_ws, size_t ws_size,
                              hipStream_t stream) {
    const int* ids   = (const int*)d_in[0];
    const float* emb = (const float*)d_in[1];
    const float* kl  = (const float*)d_in[2];
    const float* rk  = (const float*)d_in[3];
    const float* bl  = (const float*)d_in[4];
    const float* W1  = (const float*)d_in[5];
    const float* b1  = (const float*)d_in[6];
    const float* W2  = (const float*)d_in[7];
    const float* b2  = (const float*)d_in[8];
    float* out = (float*)d_out;

    char* ws = (char*)d_ws;
    const size_t XG_ELEMS = (size_t)BB * TT * GG;   // 8,388,608
    const size_t H_ELEMS  = (size_t)BB * TT * DD;   // 2,097,152
    float* xg   = (float*)ws;
    float* h    = (float*)(ws + XG_ELEMS * 4);
    float* ctx  = (float*)(ws + (XG_ELEMS + H_ELEMS) * 4);
    int* list   = (int*)  (ws + (XG_ELEMS + 2 * H_ELEMS) * 4);

    k_xg<<<512, 128, 0, stream>>>(ids, emb, kl, bl, xg);
    k_lstm_scan<<<BB + 1, 64, 0, stream>>>(xg, rk, h, ids, list, out + BB * DD);
    k_attn<<<BB * 8, 256, 0, stream>>>(h, ctx);
    k_ymlp<<<BB, 256, 0, stream>>>(ctx, h, W1, b1, W2, b2, out);
}